// Round 4
// baseline (600.607 us; speedup 1.0000x reference)
//
#include <hip/hip_runtime.h>
#include <math.h>

// GNNMLP via f16 MFMA. G=131072 groups x 6 agents x 64 feats.
// R4: occupancy push. block=1024 (16 waves), LDS = 100KB weight img + 16 x
// 2.25KB f16 wave-private slabs = 136 KB -> 1 block/CU but 16 waves/CU
// (4/SIMD, was 2). Slab is f16: storeC converts once (identical values to
// old loadA-side convert), loadA is a bare ds_read_b128 (conflict-free:
// stride 72 halves -> banks 4*(col+quad)+c, uniform).
// MFMA 16x16x32 f16 layouts (m89/m120-verified family):
//   A[m][k]: m=lane&15, k=(lane>>4)*8+j     B[k][n]: n=lane&15, k=(lane>>4)*8+j
//   C/D:     col=lane&15, row=(lane>>4)*4+reg

typedef _Float16 f16;
typedef _Float16 half8_t __attribute__((ext_vector_type(8)));
typedef float    float4_t __attribute__((ext_vector_type(4)));

#define NW 16           // waves per block
#define NB 2            // batches (16 groups) per wave
#define SLABH (16*72)   // wave slab: 16 rows x 72 halves (pad 8: aligned b128)
#define IMG_HALFS 51200 // 12*4096 + 2*1024

__device__ __forceinline__ int swz_off(int n, int k) {
    // matrix-local half offset for logical element (n, k): row n (64 halfs),
    // octet (k>>3) XOR'd with n&7, j = k&7 contiguous.
    return n * 64 + (((k >> 3) ^ (n & 7)) << 3) + (k & 7);
}

__device__ __forceinline__ float fast_tanh(float x) {
    float e = __expf(2.0f * x);
    return 1.0f - 2.0f / (e + 1.0f);
}

__device__ __forceinline__ float4_t max4(float4_t a, float4_t b) {
    float4_t r;
    r[0] = fmaxf(a[0], b[0]); r[1] = fmaxf(a[1], b[1]);
    r[2] = fmaxf(a[2], b[2]); r[3] = fmaxf(a[3], b[3]);
    return r;
}

__device__ __forceinline__ float4_t bcast4(float v) {
    float4_t r; r[0] = v; r[1] = v; r[2] = v; r[3] = v; return r;
}

// ---------------- prep: build f16 swizzled weight image in d_ws ----------------
__global__ void prep_weights(const float* __restrict__ Wp1, const float* __restrict__ Ws1,
                             const float* __restrict__ Wn1, const float* __restrict__ Wp2,
                             const float* __restrict__ Ws2, const float* __restrict__ Wn2,
                             const float* __restrict__ MW1, const float* __restrict__ MW2,
                             const float* __restrict__ MW3, const float* __restrict__ MW4,
                             f16* __restrict__ img)
{
    const int m = blockIdx.x;
    const int tid = threadIdx.x;
    if (m < 12) {
        const float* src;
        switch (m) {
            case 0: src = Wp1; break;  case 1: src = Ws1; break;
            case 2: src = Wn1; break;  case 3: src = Wp2; break;
            case 4: src = Ws2; break;  case 5: src = Wn2; break;
            case 6: src = MW1; break;  case 7: src = MW2; break;
            case 8: src = MW3; break;  case 9: src = MW1 + 4096; break;
            case 10: src = MW2 + 4096; break; default: src = MW3 + 4096; break;
        }
        for (int e = tid; e < 4096; e += 256) {
            const int k = e >> 6, n = e & 63;           // src is W[k][n] row-major
            img[m * 4096 + swz_off(n, k)] = (f16)src[e];
        }
    } else {
        // head B image: ty0 cols 0..9 = MW4[0][k][n&1] (agents 0..4 replicated),
        // ty1 cols 10,11 = MW4[1][k][n&1]; all other cols ZERO (C-chaining).
        for (int e = tid; e < 2048; e += 256) {
            const int ty = e >> 10, rem = e & 1023;
            const int n = rem >> 6, k = rem & 63;
            float v = 0.f;
            if (ty == 0) { if (n < 10) v = MW4[k * 2 + (n & 1)]; }
            else         { if (n == 10 || n == 11) v = MW4[128 + k * 2 + (n & 1)]; }
            img[12 * 4096 + ty * 1024 + swz_off(n, k)] = (f16)v;
        }
    }
}

// ---------------- main fused kernel ----------------
__global__ __launch_bounds__(1024, 4)
void gnn_mfma(const float* __restrict__ obs, const f16* __restrict__ img,
              const float* __restrict__ bp1, const float* __restrict__ b1,
              const float* __restrict__ bp2, const float* __restrict__ b2,
              const float* __restrict__ Mb1, const float* __restrict__ Mb2,
              const float* __restrict__ Mb3, const float* __restrict__ Mb4,
              float* __restrict__ out)
{
    __shared__ __align__(16) unsigned char smem[IMG_HALFS * 2 + NW * SLABH * 2];
    f16* ldsW = (f16*)smem;

    const int tid = threadIdx.x;
    // one-time: weight image -> LDS (L2/L3-hot, 256 blocks read same 100 KB)
    for (int i = tid; i < IMG_HALFS / 8; i += 1024)
        ((float4_t*)smem)[i] = ((const float4_t*)img)[i];
    __syncthreads();

    const int w    = __builtin_amdgcn_readfirstlane(tid >> 6);
    const int l    = tid & 63;
    const int col  = l & 15;
    const int quad = l >> 4;
    f16* slab = (f16*)(smem + IMG_HALFS * 2) + w * SLABH;

    // B-frag from LDS: matrix-base (halfs), Ntile nt, Kfrag kf
    auto loadB = [&](int baseH, int nt, int kf) -> half8_t {
        const int n = nt * 16 + col;
        return *(const half8_t*)(ldsW + baseH + n * 64 + ((((kf * 4 + quad) ^ (n & 7))) << 3));
    };
    // A-frag from wave slab: rows m=col, k = kf*32+quad*8+j  (bare b128 read)
    auto loadA = [&](int kf) -> half8_t {
        return *(const half8_t*)(slab + col * 72 + kf * 32 + quad * 8);
    };
    // C-frag -> slab as f16 (row g = quad*4+r, feature nt*16+col)
    auto storeC = [&](const float4_t v, int nt) {
        #pragma unroll
        for (int r = 0; r < 4; ++r)
            slab[(quad * 4 + r) * 72 + nt * 16 + col] = (f16)v[r];
    };

    // resident conv biases (per-lane, feature = nt*16+col)
    float bp1v[4], b1v[4], bp2v[4], b2v[4];
    #pragma unroll
    for (int nt = 0; nt < 4; ++nt) {
        bp1v[nt] = bp1[nt * 16 + col];
        b1v[nt]  = b1[nt * 16 + col];
        bp2v[nt] = bp2[nt * 16 + col];
        b2v[nt]  = b2[nt * 16 + col];
    }
    const float mb4v = (col < 10) ? Mb4[col & 1] : Mb4[2 + (col & 1)];

    const int wid = blockIdx.x * NW + w;

    for (int b = 0; b < NB; ++b) {
        const int g0 = (wid * NB + b) * 16;

        // ---- obs A-frags: Mtile a = agent, row m = col = group ----
        half8_t Aobs[6][2];
        const float* orow = obs + ((size_t)(g0 + col) * 6) * 64 + quad * 8;
        #pragma unroll
        for (int a = 0; a < 6; ++a) {
            #pragma unroll
            for (int kf = 0; kf < 2; ++kf) {
                const float4_t x = *(const float4_t*)(orow + a * 64 + kf * 32);
                const float4_t y = *(const float4_t*)(orow + a * 64 + kf * 32 + 4);
                half8_t r;
                r[0] = (f16)x[0]; r[1] = (f16)x[1]; r[2] = (f16)x[2]; r[3] = (f16)x[3];
                r[4] = (f16)y[0]; r[5] = (f16)y[1]; r[6] = (f16)y[2]; r[7] = (f16)y[3];
                Aobs[a][kf] = r;
            }
        }

        // ---- conv1 pool: n1 = max_a relu(obs_a @ Wp1 + bp1) ----
        half8_t B0[4][2];
        #pragma unroll
        for (int nt = 0; nt < 4; ++nt)
            #pragma unroll
            for (int kf = 0; kf < 2; ++kf) B0[nt][kf] = loadB(0 * 4096, nt, kf);
        float4_t n1[4];
        #pragma unroll
        for (int nt = 0; nt < 4; ++nt) n1[nt] = bcast4(0.f);
        #pragma unroll
        for (int a = 0; a < 6; ++a) {
            #pragma unroll
            for (int nt = 0; nt < 4; ++nt) {
                float4_t acc = bcast4(bp1v[nt]);
                acc = __builtin_amdgcn_mfma_f32_16x16x32_f16(Aobs[a][0], B0[nt][0], acc, 0, 0, 0);
                acc = __builtin_amdgcn_mfma_f32_16x16x32_f16(Aobs[a][1], B0[nt][1], acc, 0, 0, 0);
                n1[nt] = max4(n1[nt], acc);     // relu folded (init 0)
            }
        }

        // ---- c = n1 @ Wn1 + b1 (M=16 via slab round-trip) ----
        #pragma unroll
        for (int nt = 0; nt < 4; ++nt) storeC(n1[nt], nt);
        {
            const half8_t a0 = loadA(0), a1 = loadA(1);
            #pragma unroll
            for (int nt = 0; nt < 4; ++nt) {
                float4_t acc = bcast4(b1v[nt]);
                acc = __builtin_amdgcn_mfma_f32_16x16x32_f16(a0, loadB(2 * 4096, nt, 0), acc, 0, 0, 0);
                acc = __builtin_amdgcn_mfma_f32_16x16x32_f16(a1, loadB(2 * 4096, nt, 1), acc, 0, 0, 0);
                n1[nt] = acc;                    // reuse n1 regs as c
            }
        }

        // ---- per agent: h_a = tanh(obs_a@Ws1 + c); hbar += h; n2 = max relu(h_a@Wp2+bp2) ----
        half8_t B1[4][2], B3[4][2];
        #pragma unroll
        for (int nt = 0; nt < 4; ++nt)
            #pragma unroll
            for (int kf = 0; kf < 2; ++kf) {
                B1[nt][kf] = loadB(1 * 4096, nt, kf);
                B3[nt][kf] = loadB(3 * 4096, nt, kf);
            }
        float4_t hbar[4], n2[4];
        #pragma unroll
        for (int nt = 0; nt < 4; ++nt) { hbar[nt] = bcast4(0.f); n2[nt] = bcast4(0.f); }
        #pragma unroll
        for (int a = 0; a < 6; ++a) {
            #pragma unroll
            for (int nt = 0; nt < 4; ++nt) {
                float4_t acc = n1[nt];           // c
                acc = __builtin_amdgcn_mfma_f32_16x16x32_f16(Aobs[a][0], B1[nt][0], acc, 0, 0, 0);
                acc = __builtin_amdgcn_mfma_f32_16x16x32_f16(Aobs[a][1], B1[nt][1], acc, 0, 0, 0);
                #pragma unroll
                for (int r = 0; r < 4; ++r) acc[r] = fast_tanh(acc[r]);
                hbar[nt] += acc;
                storeC(acc, nt);
            }
            const half8_t ha0 = loadA(0), ha1 = loadA(1);
            #pragma unroll
            for (int nt = 0; nt < 4; ++nt) {
                float4_t q = bcast4(bp2v[nt]);
                q = __builtin_amdgcn_mfma_f32_16x16x32_f16(ha0, B3[nt][0], q, 0, 0, 0);
                q = __builtin_amdgcn_mfma_f32_16x16x32_f16(ha1, B3[nt][1], q, 0, 0, 0);
                n2[nt] = max4(n2[nt], q);
            }
        }
        #pragma unroll
        for (int nt = 0; nt < 4; ++nt) hbar[nt] *= (1.0f / 6.0f);

        // ---- res = hbar @ Ws2 + n2 @ Wn2 + b2 ----
        float4_t rres[4];
        #pragma unroll
        for (int nt = 0; nt < 4; ++nt) storeC(hbar[nt], nt);
        {
            const half8_t a0 = loadA(0), a1 = loadA(1);
            #pragma unroll
            for (int nt = 0; nt < 4; ++nt) {
                float4_t acc = bcast4(b2v[nt]);
                acc = __builtin_amdgcn_mfma_f32_16x16x32_f16(a0, loadB(4 * 4096, nt, 0), acc, 0, 0, 0);
                acc = __builtin_amdgcn_mfma_f32_16x16x32_f16(a1, loadB(4 * 4096, nt, 1), acc, 0, 0, 0);
                rres[nt] = acc;
            }
        }
        #pragma unroll
        for (int nt = 0; nt < 4; ++nt) storeC(n2[nt], nt);
        {
            const half8_t a0 = loadA(0), a1 = loadA(1);
            #pragma unroll
            for (int nt = 0; nt < 4; ++nt) {
                rres[nt] = __builtin_amdgcn_mfma_f32_16x16x32_f16(a0, loadB(5 * 4096, nt, 0), rres[nt], 0, 0, 0);
                rres[nt] = __builtin_amdgcn_mfma_f32_16x16x32_f16(a1, loadB(5 * 4096, nt, 1), rres[nt], 0, 0, 0);
            }
        }

        // ---- per-type 3-layer relu MLP; keep x3 A-frags for the head ----
        half8_t x3f[2][2];
        #pragma unroll
        for (int ty = 0; ty < 2; ++ty) {
            #pragma unroll
            for (int nt = 0; nt < 4; ++nt) storeC(rres[nt], nt);
            half8_t xa0 = loadA(0), xa1 = loadA(1);
            #pragma unroll
            for (int layer = 0; layer < 3; ++layer) {
                const int baseH = (6 + ty * 3 + layer) * 4096;
                const float* Mb = (layer == 0 ? Mb1 : layer == 1 ? Mb2 : Mb3) + ty * 64;
                #pragma unroll
                for (int nt = 0; nt < 4; ++nt) {
                    float4_t acc = bcast4(Mb[nt * 16 + col]);
                    acc = __builtin_amdgcn_mfma_f32_16x16x32_f16(xa0, loadB(baseH, nt, 0), acc, 0, 0, 0);
                    acc = __builtin_amdgcn_mfma_f32_16x16x32_f16(xa1, loadB(baseH, nt, 1), acc, 0, 0, 0);
                    acc = max4(acc, bcast4(0.f));   // relu
                    storeC(acc, nt);
                }
                xa0 = loadA(0); xa1 = loadA(1);
            }
            x3f[ty][0] = xa0; x3f[ty][1] = xa1;
        }

        // ---- head: one chained MFMA pair per type; D cols 0..11 = out[g][:] ----
        float4_t d = bcast4(0.f);
        d = __builtin_amdgcn_mfma_f32_16x16x32_f16(x3f[0][0], loadB(12 * 4096, 0, 0), d, 0, 0, 0);
        d = __builtin_amdgcn_mfma_f32_16x16x32_f16(x3f[0][1], loadB(12 * 4096, 0, 1), d, 0, 0, 0);
        d = __builtin_amdgcn_mfma_f32_16x16x32_f16(x3f[1][0], loadB(12 * 4096 + 1024, 0, 0), d, 0, 0, 0);
        d = __builtin_amdgcn_mfma_f32_16x16x32_f16(x3f[1][1], loadB(12 * 4096 + 1024, 0, 1), d, 0, 0, 0);

        if (col < 12) {
            #pragma unroll
            for (int r = 0; r < 4; ++r) {
                const float v = fast_tanh(d[r] + mb4v);
                out[(size_t)(g0 + quad * 4 + r) * 12 + col] = v;
            }
        }
    }
}

extern "C" void kernel_launch(void* const* d_in, const int* in_sizes, int n_in,
                              void* d_out, int out_size, void* d_ws, size_t ws_size,
                              hipStream_t stream)
{
    const float* obs = (const float*)d_in[0];
    const float* Wp1 = (const float*)d_in[1];
    const float* bp1 = (const float*)d_in[2];
    const float* Ws1 = (const float*)d_in[3];
    const float* Wn1 = (const float*)d_in[4];
    const float* b1  = (const float*)d_in[5];
    const float* Wp2 = (const float*)d_in[6];
    const float* bp2 = (const float*)d_in[7];
    const float* Ws2 = (const float*)d_in[8];
    const float* Wn2 = (const float*)d_in[9];
    const float* b2  = (const float*)d_in[10];
    const float* MW1 = (const float*)d_in[11];
    const float* Mb1 = (const float*)d_in[12];
    const float* MW2 = (const float*)d_in[13];
    const float* Mb2 = (const float*)d_in[14];
    const float* MW3 = (const float*)d_in[15];
    const float* Mb3 = (const float*)d_in[16];
    const float* MW4 = (const float*)d_in[17];
    const float* Mb4 = (const float*)d_in[18];
    float* out = (float*)d_out;
    f16* img = (f16*)d_ws;   // 51200 halfs = 100 KB

    hipLaunchKernelGGL(prep_weights, dim3(13), dim3(256), 0, stream,
                       Wp1, Ws1, Wn1, Wp2, Ws2, Wn2, MW1, MW2, MW3, MW4, img);
    // 256 blocks x 16 waves x NB=2 batches x 16 groups = 131072
    hipLaunchKernelGGL(gnn_mfma, dim3(256), dim3(1024), 0, stream,
                       obs, img, bp1, b1, bp2, b2, Mb1, Mb2, Mb3, Mb4, out);
}

// Round 5
// 512.626 us; speedup vs baseline: 1.1716x; 1.1716x over previous
//
#include <hip/hip_runtime.h>
#include <math.h>

// GNNMLP via f16 MFMA. G=131072 groups x 6 agents x 64 feats.
// R5: R3 body (512 thr, 128 VGPR, no spill) + occupancy via LDS diet:
//   LDS holds conv weights (6x4096 halfs = 48KB) + head (4KB) + 8 f16 wave
//   slabs (18KB) = 70KB -> 2 blocks/CU = 16 waves/CU (4/SIMD, 2x R3).
//   MLP B-frags read straight from the global img (L2/L3-hot, ~1KB/frag/wave).
//   R4 lesson: never squeeze VGPRs below ~128 here -- 1024-thr config spilled
//   (VGPR 64, WRITE_SIZE 536MB) and regressed 2x.
// MFMA 16x16x32 f16 layouts (m89/m120-verified family):
//   A[m][k]: m=lane&15, k=(lane>>4)*8+j     B[k][n]: n=lane&15, k=(lane>>4)*8+j
//   C/D:     col=lane&15, row=(lane>>4)*4+reg

typedef _Float16 f16;
typedef _Float16 half8_t __attribute__((ext_vector_type(8)));
typedef float    float4_t __attribute__((ext_vector_type(4)));

#define NW 8             // waves per block
#define NB 2             // batches (16 groups) per wave
#define SLABH (16*72)    // wave slab: 16 rows x 72 halves (pad 8: aligned b128)
#define IMG_HALFS 51200  // full img in d_ws: 12*4096 + 2*1024
#define LDS_CONV 24576   // 6 conv matrices in LDS (halfs)
#define LDS_HEAD 2048    // head image in LDS (halfs)

__device__ __forceinline__ int swz_off(int n, int k) {
    // matrix-local half offset for logical (n, k): row n (64 halfs),
    // octet (k>>3) XOR'd with n&7, j = k&7 contiguous.
    return n * 64 + (((k >> 3) ^ (n & 7)) << 3) + (k & 7);
}

__device__ __forceinline__ float fast_tanh(float x) {
    float e = __expf(2.0f * x);
    return 1.0f - 2.0f / (e + 1.0f);
}

__device__ __forceinline__ float4_t max4(float4_t a, float4_t b) {
    float4_t r;
    r[0] = fmaxf(a[0], b[0]); r[1] = fmaxf(a[1], b[1]);
    r[2] = fmaxf(a[2], b[2]); r[3] = fmaxf(a[3], b[3]);
    return r;
}

__device__ __forceinline__ float4_t bcast4(float v) {
    float4_t r; r[0] = v; r[1] = v; r[2] = v; r[3] = v; return r;
}

// ---------------- prep: build f16 swizzled weight image in d_ws ----------------
__global__ void prep_weights(const float* __restrict__ Wp1, const float* __restrict__ Ws1,
                             const float* __restrict__ Wn1, const float* __restrict__ Wp2,
                             const float* __restrict__ Ws2, const float* __restrict__ Wn2,
                             const float* __restrict__ MW1, const float* __restrict__ MW2,
                             const float* __restrict__ MW3, const float* __restrict__ MW4,
                             f16* __restrict__ img)
{
    const int m = blockIdx.x;
    const int tid = threadIdx.x;
    if (m < 12) {
        const float* src;
        switch (m) {
            case 0: src = Wp1; break;  case 1: src = Ws1; break;
            case 2: src = Wn1; break;  case 3: src = Wp2; break;
            case 4: src = Ws2; break;  case 5: src = Wn2; break;
            case 6: src = MW1; break;  case 7: src = MW2; break;
            case 8: src = MW3; break;  case 9: src = MW1 + 4096; break;
            case 10: src = MW2 + 4096; break; default: src = MW3 + 4096; break;
        }
        for (int e = tid; e < 4096; e += 256) {
            const int k = e >> 6, n = e & 63;           // src is W[k][n] row-major
            img[m * 4096 + swz_off(n, k)] = (f16)src[e];
        }
    } else {
        // head B image: ty0 cols 0..9 = MW4[0][k][n&1] (agents 0..4 replicated),
        // ty1 cols 10,11 = MW4[1][k][n&1]; all other cols ZERO (C-chaining).
        for (int e = tid; e < 2048; e += 256) {
            const int ty = e >> 10, rem = e & 1023;
            const int n = rem >> 6, k = rem & 63;
            float v = 0.f;
            if (ty == 0) { if (n < 10) v = MW4[k * 2 + (n & 1)]; }
            else         { if (n == 10 || n == 11) v = MW4[128 + k * 2 + (n & 1)]; }
            img[12 * 4096 + ty * 1024 + swz_off(n, k)] = (f16)v;
        }
    }
}

// ---------------- main fused kernel ----------------
__global__ __launch_bounds__(512, 2)
void gnn_mfma(const float* __restrict__ obs, const f16* __restrict__ img,
              const float* __restrict__ bp1, const float* __restrict__ b1,
              const float* __restrict__ bp2, const float* __restrict__ b2,
              const float* __restrict__ Mb1, const float* __restrict__ Mb2,
              const float* __restrict__ Mb3, const float* __restrict__ Mb4,
              float* __restrict__ out)
{
    __shared__ __align__(16) unsigned char smem[(LDS_CONV + LDS_HEAD) * 2 + NW * SLABH * 2];
    f16* ldsW = (f16*)smem;

    const int tid = threadIdx.x;
    // one-time: conv weights + head -> LDS (L2/L3-hot)
    for (int i = tid; i < LDS_CONV / 8; i += 512)
        ((float4_t*)ldsW)[i] = ((const float4_t*)img)[i];
    if (tid < LDS_HEAD / 8)
        ((float4_t*)(ldsW + LDS_CONV))[tid] = ((const float4_t*)(img + 12 * 4096))[tid];
    __syncthreads();

    const int w    = __builtin_amdgcn_readfirstlane(tid >> 6);
    const int l    = tid & 63;
    const int col  = l & 15;
    const int quad = l >> 4;
    f16* slab = (f16*)(smem + (LDS_CONV + LDS_HEAD) * 2) + w * SLABH;

    // B-frag from LDS: matrix-base (halfs), Ntile nt, Kfrag kf
    auto loadB = [&](int baseH, int nt, int kf) -> half8_t {
        const int n = nt * 16 + col;
        return *(const half8_t*)(ldsW + baseH + n * 64 + ((((kf * 4 + quad) ^ (n & 7))) << 3));
    };
    // B-frag straight from global img (MLP matrices; L2/L3-hot)
    auto loadBg = [&](const f16* __restrict__ gW, int nt, int kf) -> half8_t {
        const int n = nt * 16 + col;
        return *(const half8_t*)(gW + n * 64 + ((((kf * 4 + quad) ^ (n & 7))) << 3));
    };
    // A-frag from wave slab: rows m=col, k = kf*32+quad*8+j  (bare b128 read)
    auto loadA = [&](int kf) -> half8_t {
        return *(const half8_t*)(slab + col * 72 + kf * 32 + quad * 8);
    };
    // C-frag -> slab as f16 (row g = quad*4+r, feature nt*16+col)
    auto storeC = [&](const float4_t v, int nt) {
        #pragma unroll
        for (int r = 0; r < 4; ++r)
            slab[(quad * 4 + r) * 72 + nt * 16 + col] = (f16)v[r];
    };

    // resident conv biases (per-lane, feature = nt*16+col)
    float bp1v[4], b1v[4], bp2v[4], b2v[4];
    #pragma unroll
    for (int nt = 0; nt < 4; ++nt) {
        bp1v[nt] = bp1[nt * 16 + col];
        b1v[nt]  = b1[nt * 16 + col];
        bp2v[nt] = bp2[nt * 16 + col];
        b2v[nt]  = b2[nt * 16 + col];
    }
    const float mb4v = (col < 10) ? Mb4[col & 1] : Mb4[2 + (col & 1)];

    const int wid = blockIdx.x * NW + w;

    for (int b = 0; b < NB; ++b) {
        const int g0 = (wid * NB + b) * 16;

        // ---- obs A-frags: Mtile a = agent, row m = col = group ----
        half8_t Aobs[6][2];
        const float* orow = obs + ((size_t)(g0 + col) * 6) * 64 + quad * 8;
        #pragma unroll
        for (int a = 0; a < 6; ++a) {
            #pragma unroll
            for (int kf = 0; kf < 2; ++kf) {
                const float4_t x = *(const float4_t*)(orow + a * 64 + kf * 32);
                const float4_t y = *(const float4_t*)(orow + a * 64 + kf * 32 + 4);
                half8_t r;
                r[0] = (f16)x[0]; r[1] = (f16)x[1]; r[2] = (f16)x[2]; r[3] = (f16)x[3];
                r[4] = (f16)y[0]; r[5] = (f16)y[1]; r[6] = (f16)y[2]; r[7] = (f16)y[3];
                Aobs[a][kf] = r;
            }
        }

        // ---- conv1 pool: n1 = max_a relu(obs_a @ Wp1 + bp1) ----
        half8_t B0[4][2];
        #pragma unroll
        for (int nt = 0; nt < 4; ++nt)
            #pragma unroll
            for (int kf = 0; kf < 2; ++kf) B0[nt][kf] = loadB(0 * 4096, nt, kf);
        float4_t n1[4];
        #pragma unroll
        for (int nt = 0; nt < 4; ++nt) n1[nt] = bcast4(0.f);
        #pragma unroll
        for (int a = 0; a < 6; ++a) {
            #pragma unroll
            for (int nt = 0; nt < 4; ++nt) {
                float4_t acc = bcast4(bp1v[nt]);
                acc = __builtin_amdgcn_mfma_f32_16x16x32_f16(Aobs[a][0], B0[nt][0], acc, 0, 0, 0);
                acc = __builtin_amdgcn_mfma_f32_16x16x32_f16(Aobs[a][1], B0[nt][1], acc, 0, 0, 0);
                n1[nt] = max4(n1[nt], acc);     // relu folded (init 0)
            }
        }

        // ---- c = n1 @ Wn1 + b1 (M=16 via slab round-trip) ----
        #pragma unroll
        for (int nt = 0; nt < 4; ++nt) storeC(n1[nt], nt);
        {
            const half8_t a0 = loadA(0), a1 = loadA(1);
            #pragma unroll
            for (int nt = 0; nt < 4; ++nt) {
                float4_t acc = bcast4(b1v[nt]);
                acc = __builtin_amdgcn_mfma_f32_16x16x32_f16(a0, loadB(2 * 4096, nt, 0), acc, 0, 0, 0);
                acc = __builtin_amdgcn_mfma_f32_16x16x32_f16(a1, loadB(2 * 4096, nt, 1), acc, 0, 0, 0);
                n1[nt] = acc;                    // reuse n1 regs as c
            }
        }

        // ---- per agent: h_a = tanh(obs_a@Ws1 + c); hbar += h; n2 = max relu(h_a@Wp2+bp2) ----
        half8_t B1[4][2], B3[4][2];
        #pragma unroll
        for (int nt = 0; nt < 4; ++nt)
            #pragma unroll
            for (int kf = 0; kf < 2; ++kf) {
                B1[nt][kf] = loadB(1 * 4096, nt, kf);
                B3[nt][kf] = loadB(3 * 4096, nt, kf);
            }
        float4_t hbar[4], n2[4];
        #pragma unroll
        for (int nt = 0; nt < 4; ++nt) { hbar[nt] = bcast4(0.f); n2[nt] = bcast4(0.f); }
        #pragma unroll
        for (int a = 0; a < 6; ++a) {
            #pragma unroll
            for (int nt = 0; nt < 4; ++nt) {
                float4_t acc = n1[nt];           // c
                acc = __builtin_amdgcn_mfma_f32_16x16x32_f16(Aobs[a][0], B1[nt][0], acc, 0, 0, 0);
                acc = __builtin_amdgcn_mfma_f32_16x16x32_f16(Aobs[a][1], B1[nt][1], acc, 0, 0, 0);
                #pragma unroll
                for (int r = 0; r < 4; ++r) acc[r] = fast_tanh(acc[r]);
                hbar[nt] += acc;
                storeC(acc, nt);
            }
            const half8_t ha0 = loadA(0), ha1 = loadA(1);
            #pragma unroll
            for (int nt = 0; nt < 4; ++nt) {
                float4_t q = bcast4(bp2v[nt]);
                q = __builtin_amdgcn_mfma_f32_16x16x32_f16(ha0, B3[nt][0], q, 0, 0, 0);
                q = __builtin_amdgcn_mfma_f32_16x16x32_f16(ha1, B3[nt][1], q, 0, 0, 0);
                n2[nt] = max4(n2[nt], q);
            }
        }
        #pragma unroll
        for (int nt = 0; nt < 4; ++nt) hbar[nt] *= (1.0f / 6.0f);

        // ---- res = hbar @ Ws2 + n2 @ Wn2 + b2 ----
        float4_t rres[4];
        #pragma unroll
        for (int nt = 0; nt < 4; ++nt) storeC(hbar[nt], nt);
        {
            const half8_t a0 = loadA(0), a1 = loadA(1);
            #pragma unroll
            for (int nt = 0; nt < 4; ++nt) {
                float4_t acc = bcast4(b2v[nt]);
                acc = __builtin_amdgcn_mfma_f32_16x16x32_f16(a0, loadB(4 * 4096, nt, 0), acc, 0, 0, 0);
                acc = __builtin_amdgcn_mfma_f32_16x16x32_f16(a1, loadB(4 * 4096, nt, 1), acc, 0, 0, 0);
                rres[nt] = acc;
            }
        }
        #pragma unroll
        for (int nt = 0; nt < 4; ++nt) storeC(n2[nt], nt);
        {
            const half8_t a0 = loadA(0), a1 = loadA(1);
            #pragma unroll
            for (int nt = 0; nt < 4; ++nt) {
                rres[nt] = __builtin_amdgcn_mfma_f32_16x16x32_f16(a0, loadB(5 * 4096, nt, 0), rres[nt], 0, 0, 0);
                rres[nt] = __builtin_amdgcn_mfma_f32_16x16x32_f16(a1, loadB(5 * 4096, nt, 1), rres[nt], 0, 0, 0);
            }
        }

        // ---- per-type 3-layer relu MLP (B-frags from global img); keep x3 for head ----
        half8_t x3f[2][2];
        #pragma unroll
        for (int ty = 0; ty < 2; ++ty) {
            #pragma unroll
            for (int nt = 0; nt < 4; ++nt) storeC(rres[nt], nt);
            half8_t xa0 = loadA(0), xa1 = loadA(1);
            #pragma unroll
            for (int layer = 0; layer < 3; ++layer) {
                const f16* gW = img + (6 + ty * 3 + layer) * 4096;
                const float* Mb = (layer == 0 ? Mb1 : layer == 1 ? Mb2 : Mb3) + ty * 64;
                #pragma unroll
                for (int nt = 0; nt < 4; ++nt) {
                    float4_t acc = bcast4(Mb[nt * 16 + col]);
                    acc = __builtin_amdgcn_mfma_f32_16x16x32_f16(xa0, loadBg(gW, nt, 0), acc, 0, 0, 0);
                    acc = __builtin_amdgcn_mfma_f32_16x16x32_f16(xa1, loadBg(gW, nt, 1), acc, 0, 0, 0);
                    acc = max4(acc, bcast4(0.f));   // relu
                    storeC(acc, nt);
                }
                xa0 = loadA(0); xa1 = loadA(1);
            }
            x3f[ty][0] = xa0; x3f[ty][1] = xa1;
        }

        // ---- head: chained MFMA pairs; D cols 0..11 = out[g][:] ----
        float4_t d = bcast4(0.f);
        d = __builtin_amdgcn_mfma_f32_16x16x32_f16(x3f[0][0], loadB(LDS_CONV, 0, 0), d, 0, 0, 0);
        d = __builtin_amdgcn_mfma_f32_16x16x32_f16(x3f[0][1], loadB(LDS_CONV, 0, 1), d, 0, 0, 0);
        d = __builtin_amdgcn_mfma_f32_16x16x32_f16(x3f[1][0], loadB(LDS_CONV + 1024, 0, 0), d, 0, 0, 0);
        d = __builtin_amdgcn_mfma_f32_16x16x32_f16(x3f[1][1], loadB(LDS_CONV + 1024, 0, 1), d, 0, 0, 0);

        if (col < 12) {
            #pragma unroll
            for (int r = 0; r < 4; ++r) {
                const float v = fast_tanh(d[r] + mb4v);
                out[(size_t)(g0 + quad * 4 + r) * 12 + col] = v;
            }
        }
    }
}

extern "C" void kernel_launch(void* const* d_in, const int* in_sizes, int n_in,
                              void* d_out, int out_size, void* d_ws, size_t ws_size,
                              hipStream_t stream)
{
    const float* obs = (const float*)d_in[0];
    const float* Wp1 = (const float*)d_in[1];
    const float* bp1 = (const float*)d_in[2];
    const float* Ws1 = (const float*)d_in[3];
    const float* Wn1 = (const float*)d_in[4];
    const float* b1  = (const float*)d_in[5];
    const float* Wp2 = (const float*)d_in[6];
    const float* bp2 = (const float*)d_in[7];
    const float* Ws2 = (const float*)d_in[8];
    const float* Wn2 = (const float*)d_in[9];
    const float* b2  = (const float*)d_in[10];
    const float* MW1 = (const float*)d_in[11];
    const float* Mb1 = (const float*)d_in[12];
    const float* MW2 = (const float*)d_in[13];
    const float* Mb2 = (const float*)d_in[14];
    const float* MW3 = (const float*)d_in[15];
    const float* Mb3 = (const float*)d_in[16];
    const float* MW4 = (const float*)d_in[17];
    const float* Mb4 = (const float*)d_in[18];
    float* out = (float*)d_out;
    f16* img = (f16*)d_ws;   // 51200 halfs = 100 KB

    hipLaunchKernelGGL(prep_weights, dim3(13), dim3(256), 0, stream,
                       Wp1, Ws1, Wn1, Wp2, Ws2, Wn2, MW1, MW2, MW3, MW4, img);
    // 512 blocks x 8 waves x NB=2 batches x 16 groups = 131072
    hipLaunchKernelGGL(gnn_mfma, dim3(512), dim3(512), 0, stream,
                       obs, img, bp1, b1, bp2, b2, Mb1, Mb2, Mb3, Mb4, out);
}